// Round 8
// baseline (52.372 us; speedup 1.0000x reference)
//
#include <hip/hip_runtime.h>

#define B_ 128
#define S_ 512
#define H_ 1024
#define L_ 9
#define GBLK 544  // dense-row blocks: covers total <= 34816 (mean 32768, +16 sigma)

// ---- Kernel A: per-batch compaction map + pad-row outputs (wave-parallel) ----
__global__ __launch_bounds__(256) void prep_kernel(
    const int* __restrict__ valid, const float* __restrict__ bias,
    float* __restrict__ out, int* __restrict__ ws_src, int* __restrict__ ws_nv) {
    __shared__ int cnt[8];
    const int lane = threadIdx.x & 63;
    const int wv = threadIdx.x >> 6;
    const int b = blockIdx.x;
    const int* vrow = valid + (size_t)b * S_;

    int v0 = vrow[128 * wv + lane];
    int v1 = vrow[128 * wv + 64 + lane];
    unsigned long long m0 = __ballot(v0 != 0);
    unsigned long long m1 = __ballot(v1 != 0);
    if (lane == 0) { cnt[2 * wv] = __popcll(m0); cnt[2 * wv + 1] = __popcll(m1); }
    __syncthreads();

    int base0 = 0, total = 0;
#pragma unroll
    for (int k = 0; k < 8; ++k) {
        if (k < 2 * wv) base0 += cnt[k];
        total += cnt[k];
    }
    int base1 = base0 + cnt[2 * wv];
    if (v0) ws_src[b * S_ + base0 + __popcll(m0 & ((1ull << lane) - 1ull))] =
        128 * wv + lane;
    if (v1) ws_src[b * S_ + base1 + __popcll(m1 & ((1ull << lane) - 1ull))] =
        128 * wv + 64 + lane;
    if (threadIdx.x == 0) ws_nv[b] = total;

    // pad rows [total, 512): softmax(bias)
    float pv[L_];
    float mx = bias[0];
#pragma unroll
    for (int l = 1; l < L_; ++l) mx = fmaxf(mx, bias[l]);
    float s = 0.f;
#pragma unroll
    for (int l = 0; l < L_; ++l) { pv[l] = expf(bias[l] - mx); s += pv[l]; }
    float inv = 1.f / s;
#pragma unroll
    for (int l = 0; l < L_; ++l) pv[l] *= inv;
    for (int j = total + threadIdx.x; j < S_; j += 256) {
        float* op = out + ((size_t)b * S_ + j) * L_;
#pragma unroll
        for (int l = 0; l < L_; ++l) op[l] = pv[l];
    }
}

// ---- Kernel B: window-wave GEMM. Wave wv owns h in [256wv, 256wv+256). ----
// Each wave-instr reads ONE row's 1KB window contiguously (fill pattern);
// W slice (36 floats) per lane lives in registers; no LDS in the loop.
// 4-row folded butterfly reduces 64 lanes; cross-wave combine in LDS at end.
__global__ __launch_bounds__(256, 2) void gemm_kernel(
    const float* __restrict__ seq, const float* __restrict__ Wm,
    const float* __restrict__ bias, const int* __restrict__ ws_src,
    const int* __restrict__ ws_nv, float* __restrict__ out) {
    __shared__ int offs[B_ + 1];
    __shared__ int srow[64], orow[64];
    __shared__ float red[4][64][12];  // stride 12 -> 48B rows, 16B aligned

    const int lane = threadIdx.x & 63;
    const int wv = __builtin_amdgcn_readfirstlane(threadIdx.x >> 6);

    if (threadIdx.x < 64) {  // 128-wide exclusive prefix of ws_nv
        int s0 = ws_nv[lane], s1 = ws_nv[64 + lane];
#pragma unroll
        for (int d = 1; d < 64; d <<= 1) {
            int t0 = __shfl_up(s0, d, 64), t1 = __shfl_up(s1, d, 64);
            if (lane >= d) { s0 += t0; s1 += t1; }
        }
        int tot0 = __shfl(s0, 63, 64);
        offs[1 + lane] = s0;
        offs[65 + lane] = tot0 + s1;
        if (lane == 0) offs[0] = 0;
    }
    __syncthreads();

    const int total = offs[B_];
    const int G0 = blockIdx.x * 64;
    if (G0 >= total) return;  // block-uniform

    if (threadIdx.x < 64) {
        const int G = G0 + threadIdx.x;
        int o = 0, sa = -1;
        if (G < total) {
            int lo = 0, hi = B_;
            while (hi - lo > 1) {
                int mid = (lo + hi) >> 1;
                if (offs[mid] <= G) lo = mid; else hi = mid;
            }
            int j = G - offs[lo];
            o = lo * S_ + j;
            sa = lo * S_ + ws_src[o];
        }
        srow[threadIdx.x] = sa;  // -1 = beyond total (prep wrote pad output)
        orow[threadIdx.x] = o;
    }
    __syncthreads();

    // per-lane W registers: 9 float4 = W[256wv+4lane .. +4][9] (16B aligned)
    float wf[36];
    {
        const float4* wp = (const float4*)(Wm + (size_t)(256 * wv + 4 * lane) * L_);
#pragma unroll
        for (int j = 0; j < 9; ++j) *(float4*)&wf[4 * j] = wp[j];
    }

    auto rowptr = [&](int r) {
        int sa = srow[r];
        return (const float4*)(seq + (size_t)(sa < 0 ? 0 : sa) * H_ + 256 * wv) + lane;
    };

    auto compute = [&](int t, float4 x0, float4 x1, float4 x2, float4 x3) {
        float c0[4] = {x0.x, x0.y, x0.z, x0.w};
        float c1[4] = {x1.x, x1.y, x1.z, x1.w};
        float c2[4] = {x2.x, x2.y, x2.z, x2.w};
        float c3[4] = {x3.x, x3.y, x3.z, x3.w};
        float p0[L_], p1[L_], p2[L_], p3[L_];
#pragma unroll
        for (int l = 0; l < L_; ++l) { p0[l] = 0.f; p1[l] = 0.f; p2[l] = 0.f; p3[l] = 0.f; }
#pragma unroll
        for (int c = 0; c < 4; ++c)
#pragma unroll
            for (int l = 0; l < L_; ++l) {
                float w = wf[c * L_ + l];
                p0[l] = fmaf(c0[c], w, p0[l]);
                p1[l] = fmaf(c1[c], w, p1[l]);
                p2[l] = fmaf(c2[c], w, p2[l]);
                p3[l] = fmaf(c3[c], w, p3[l]);
            }
        // folded butterfly: 4 rows -> one row per 16-lane group, rmap {0,2,1,3}
        const bool lo32 = (lane & 32) == 0;
        const bool lo16 = (lane & 16) == 0;
        float a[L_], b[L_], cc[L_];
#pragma unroll
        for (int l = 0; l < L_; ++l) {
            float s0 = p0[l] + __shfl_xor(p0[l], 32);
            float s1 = p1[l] + __shfl_xor(p1[l], 32);
            float s2 = p2[l] + __shfl_xor(p2[l], 32);
            float s3 = p3[l] + __shfl_xor(p3[l], 32);
            a[l] = lo32 ? s0 : s1;
            b[l] = lo32 ? s2 : s3;
        }
#pragma unroll
        for (int l = 0; l < L_; ++l) {
            float sa = a[l] + __shfl_xor(a[l], 16);
            float sb = b[l] + __shfl_xor(b[l], 16);
            cc[l] = lo16 ? sa : sb;
        }
#pragma unroll
        for (int m = 8; m >= 1; m >>= 1)
#pragma unroll
            for (int l = 0; l < L_; ++l) cc[l] += __shfl_xor(cc[l], m);

        if ((lane & 15) == 0) {
            int g = lane >> 4;
            int rm = (g == 0) ? 0 : (g == 1) ? 2 : (g == 2) ? 1 : 3;
            float* rp = &red[wv][4 * t + rm][0];
            *(float4*)rp = make_float4(cc[0], cc[1], cc[2], cc[3]);
            *(float4*)(rp + 4) = make_float4(cc[4], cc[5], cc[6], cc[7]);
            rp[8] = cc[8];
        }
    };

    // ping-pong over 16 tiles of 4 rows (1-tile lookahead, ~4KB/wave in flight)
    float4 A0 = rowptr(0)[0], A1 = rowptr(1)[0], A2 = rowptr(2)[0], A3 = rowptr(3)[0];
    float4 B0, B1, B2, B3;
#pragma unroll
    for (int t = 0; t < 16; t += 2) {
        {
            int r = 4 * (t + 1);
            B0 = rowptr(r)[0]; B1 = rowptr(r + 1)[0];
            B2 = rowptr(r + 2)[0]; B3 = rowptr(r + 3)[0];
        }
        compute(t, A0, A1, A2, A3);
        if (t + 2 < 16) {
            int r = 4 * (t + 2);
            A0 = rowptr(r)[0]; A1 = rowptr(r + 1)[0];
            A2 = rowptr(r + 2)[0]; A3 = rowptr(r + 3)[0];
        }
        compute(t + 1, B0, B1, B2, B3);
    }
    __syncthreads();

    // final: thread = row; combine 4 wave partials, bias+softmax, store
    if (threadIdx.x < 64) {
        if (srow[threadIdx.x] >= 0) {
            float v[L_];
#pragma unroll
            for (int l = 0; l < L_; ++l)
                v[l] = red[0][threadIdx.x][l] + red[1][threadIdx.x][l] +
                       red[2][threadIdx.x][l] + red[3][threadIdx.x][l] + bias[l];
            float mx = v[0];
#pragma unroll
            for (int l = 1; l < L_; ++l) mx = fmaxf(mx, v[l]);
            float s = 0.f;
#pragma unroll
            for (int l = 0; l < L_; ++l) { v[l] = expf(v[l] - mx); s += v[l]; }
            float inv = 1.f / s;
            float* op = out + (size_t)orow[threadIdx.x] * L_;
#pragma unroll
            for (int l = 0; l < L_; ++l) op[l] = v[l] * inv;
        }
    }
}

extern "C" void kernel_launch(void* const* d_in, const int* in_sizes, int n_in,
                              void* d_out, int out_size, void* d_ws, size_t ws_size,
                              hipStream_t stream) {
    const float* seq = (const float*)d_in[0];   // [B,S,H] f32
    const float* W = (const float*)d_in[1];     // [H,L] f32
    const float* bias = (const float*)d_in[2];  // [L] f32
    const int* valid = (const int*)d_in[3];     // [B,S] i32
    float* out = (float*)d_out;                 // [B,S,L] f32

    int* ws_src = (int*)d_ws;        // [128*512] within-batch source indices
    int* ws_nv = ws_src + B_ * S_;   // [128] valid counts

    prep_kernel<<<dim3(B_), dim3(256), 0, stream>>>(valid, bias, out, ws_src, ws_nv);
    gemm_kernel<<<dim3(GBLK), dim3(256), 0, stream>>>(seq, W, bias, ws_src, ws_nv,
                                                      out);
}

// Round 9
// 47.564 us; speedup vs baseline: 1.1011x; 1.1011x over previous
//
#include <hip/hip_runtime.h>

#define B_ 128
#define S_ 512
#define H_ 1024
#define L_ 9
#define NWORK 512  // worker blocks (2/CU)
#define TROWS 16   // dense rows per steal unit

// ---- Kernel A: compaction map + pad-row outputs + steal-counter reset ----
__global__ __launch_bounds__(256) void prep_kernel(
    const int* __restrict__ valid, const float* __restrict__ bias,
    float* __restrict__ out, int* __restrict__ ws_src, int* __restrict__ ws_nv,
    int* __restrict__ ctr) {
    __shared__ int cnt[8];
    const int lane = threadIdx.x & 63;
    const int wv = threadIdx.x >> 6;
    const int b = blockIdx.x;
    const int* vrow = valid + (size_t)b * S_;

    if (b == 0 && threadIdx.x == 0) *ctr = 0;  // reset every launch (pre-gemm)

    int v0 = vrow[128 * wv + lane];
    int v1 = vrow[128 * wv + 64 + lane];
    unsigned long long m0 = __ballot(v0 != 0);
    unsigned long long m1 = __ballot(v1 != 0);
    if (lane == 0) { cnt[2 * wv] = __popcll(m0); cnt[2 * wv + 1] = __popcll(m1); }
    __syncthreads();

    int base0 = 0, total = 0;
#pragma unroll
    for (int k = 0; k < 8; ++k) {
        if (k < 2 * wv) base0 += cnt[k];
        total += cnt[k];
    }
    int base1 = base0 + cnt[2 * wv];
    if (v0) ws_src[b * S_ + base0 + __popcll(m0 & ((1ull << lane) - 1ull))] =
        128 * wv + lane;
    if (v1) ws_src[b * S_ + base1 + __popcll(m1 & ((1ull << lane) - 1ull))] =
        128 * wv + 64 + lane;
    if (threadIdx.x == 0) ws_nv[b] = total;

    // pad rows [total, 512): softmax(bias)
    float pv[L_];
    float mx = bias[0];
#pragma unroll
    for (int l = 1; l < L_; ++l) mx = fmaxf(mx, bias[l]);
    float s = 0.f;
#pragma unroll
    for (int l = 0; l < L_; ++l) { pv[l] = expf(bias[l] - mx); s += pv[l]; }
    float inv = 1.f / s;
#pragma unroll
    for (int l = 0; l < L_; ++l) pv[l] *= inv;
    for (int j = total + threadIdx.x; j < S_; j += 256) {
        float* op = out + ((size_t)b * S_ + j) * L_;
#pragma unroll
        for (int l = 0; l < L_; ++l) op[l] = pv[l];
    }
}

// ---- Kernel B: work-stealing GEMM. Unit = 16 dense rows; 4 waves split h ----
// Wave wv owns h-quarter [256wv,256wv+256). Lane (hl=lane&15, g=lane>>4);
// slot s covers rows 4s+g: one load instr = 4 rows x 256B = 1KB. W in LDS,
// wr[36] per it feeds 144 FMA (R6 reuse ratio). hl-butterfly ONCE per unit.
__global__ __launch_bounds__(256, 2) void gemm_kernel(
    const float* __restrict__ seq, const float* __restrict__ Wm,
    const float* __restrict__ bias, const int* __restrict__ ws_src,
    const int* __restrict__ ws_nv, int* __restrict__ ctr,
    float* __restrict__ out) {
    __shared__ __align__(16) float Wl[H_ * L_];  // 36,864 B
    __shared__ int offs[B_ + 1];
    __shared__ int srow16[TROWS], orow16[TROWS];
    __shared__ __align__(16) float red[4][TROWS][12];
    __shared__ int sh_u;

    const int tid = threadIdx.x;
    const int lane = tid & 63;
    const int wv = __builtin_amdgcn_readfirstlane(tid >> 6);
    const int hl = lane & 15;
    const int g = lane >> 4;

    if (tid < 64) {  // 128-wide exclusive prefix of ws_nv
        int s0 = ws_nv[lane], s1 = ws_nv[64 + lane];
#pragma unroll
        for (int d = 1; d < 64; d <<= 1) {
            int t0 = __shfl_up(s0, d, 64), t1 = __shfl_up(s1, d, 64);
            if (lane >= d) { s0 += t0; s1 += t1; }
        }
        int tot0 = __shfl(s0, 63, 64);
        offs[1 + lane] = s0;
        offs[65 + lane] = tot0 + s1;
        if (lane == 0) offs[0] = 0;
    }
    {  // cooperative W -> LDS
        const float4* Wg = (const float4*)Wm;
        float4* Wd = (float4*)Wl;
#pragma unroll
        for (int k = 0; k < 9; ++k) Wd[k * 256 + tid] = Wg[k * 256 + tid];
    }
    __syncthreads();

    const int total = offs[B_];
    const int ntiles = (total + TROWS - 1) / TROWS;

    for (;;) {
        if (tid == 0) sh_u = atomicAdd(ctr, 1);
        __syncthreads();  // also orders prev unit's combine vs srow overwrite
        const int u = sh_u;
        if (u >= ntiles) break;

        if (tid < TROWS) {
            int G = u * TROWS + tid;
            int sa = -1, o = 0;
            if (G < total) {
                int lo = 0, hi = B_;
                while (hi - lo > 1) {
                    int mid = (lo + hi) >> 1;
                    if (offs[mid] <= G) lo = mid; else hi = mid;
                }
                int j = G - offs[lo];
                o = lo * S_ + j;
                sa = lo * S_ + ws_src[o];
            }
            srow16[tid] = sa;
            orow16[tid] = o;
        }
        __syncthreads();

        const float* rp[4];
#pragma unroll
        for (int s = 0; s < 4; ++s) {
            int sa = srow16[4 * s + g];
            rp[s] = seq + (size_t)(sa < 0 ? 0 : sa) * H_ + 256 * wv + 4 * hl;
        }

        float acc[4][L_];
#pragma unroll
        for (int s = 0; s < 4; ++s)
#pragma unroll
            for (int l = 0; l < L_; ++l) acc[s][l] = 0.f;

#pragma unroll
        for (int it = 0; it < 4; ++it) {
            float4 xv0 = *(const float4*)(rp[0] + 64 * it);
            float4 xv1 = *(const float4*)(rp[1] + 64 * it);
            float4 xv2 = *(const float4*)(rp[2] + 64 * it);
            float4 xv3 = *(const float4*)(rp[3] + 64 * it);
            const float* wf = Wl + 2304 * wv + 576 * it + 36 * hl;
            float wr[36];
#pragma unroll
            for (int j = 0; j < 9; ++j)
                *(float4*)&wr[4 * j] = *(const float4*)(wf + 4 * j);
            float xk0[4] = {xv0.x, xv0.y, xv0.z, xv0.w};
            float xk1[4] = {xv1.x, xv1.y, xv1.z, xv1.w};
            float xk2[4] = {xv2.x, xv2.y, xv2.z, xv2.w};
            float xk3[4] = {xv3.x, xv3.y, xv3.z, xv3.w};
#pragma unroll
            for (int k = 0; k < 4; ++k)
#pragma unroll
                for (int l = 0; l < L_; ++l) {
                    float w = wr[9 * k + l];
                    acc[0][l] = fmaf(xk0[k], w, acc[0][l]);
                    acc[1][l] = fmaf(xk1[k], w, acc[1][l]);
                    acc[2][l] = fmaf(xk2[k], w, acc[2][l]);
                    acc[3][l] = fmaf(xk3[k], w, acc[3][l]);
                }
        }

        // 16-wide hl-butterfly, once per unit (xor of low 4 lane bits)
#pragma unroll
        for (int m = 1; m < 16; m <<= 1)
#pragma unroll
            for (int s = 0; s < 4; ++s)
#pragma unroll
                for (int l = 0; l < L_; ++l)
                    acc[s][l] += __shfl_xor(acc[s][l], m);

        // lanes hl<4 write slot==hl partials: row 4*hl+g
        if (hl < 4) {
            float v[12];
#pragma unroll
            for (int s = 0; s < 4; ++s)
                if (hl == s) {
#pragma unroll
                    for (int l = 0; l < L_; ++l) v[l] = acc[s][l];
                }
            float* rpo = &red[wv][4 * hl + g][0];
            *(float4*)rpo = make_float4(v[0], v[1], v[2], v[3]);
            *(float4*)(rpo + 4) = make_float4(v[4], v[5], v[6], v[7]);
            rpo[8] = v[8];
        }
        __syncthreads();

        if (tid < TROWS && srow16[tid] >= 0) {
            float v[L_];
#pragma unroll
            for (int l = 0; l < L_; ++l)
                v[l] = red[0][tid][l] + red[1][tid][l] + red[2][tid][l] +
                       red[3][tid][l] + bias[l];
            float mx = v[0];
#pragma unroll
            for (int l = 1; l < L_; ++l) mx = fmaxf(mx, v[l]);
            float s = 0.f;
#pragma unroll
            for (int l = 0; l < L_; ++l) { v[l] = expf(v[l] - mx); s += v[l]; }
            float inv = 1.f / s;
            float* op = out + (size_t)orow16[tid] * L_;
#pragma unroll
            for (int l = 0; l < L_; ++l) op[l] = v[l] * inv;
        }
    }
}

extern "C" void kernel_launch(void* const* d_in, const int* in_sizes, int n_in,
                              void* d_out, int out_size, void* d_ws, size_t ws_size,
                              hipStream_t stream) {
    const float* seq = (const float*)d_in[0];   // [B,S,H] f32
    const float* W = (const float*)d_in[1];     // [H,L] f32
    const float* bias = (const float*)d_in[2];  // [L] f32
    const int* valid = (const int*)d_in[3];     // [B,S] i32
    float* out = (float*)d_out;                 // [B,S,L] f32

    int* ws_src = (int*)d_ws;        // [128*512] within-batch source indices
    int* ws_nv = ws_src + B_ * S_;   // [128] valid counts
    int* ctr = ws_nv + B_;           // [1] steal counter

    prep_kernel<<<dim3(B_), dim3(256), 0, stream>>>(valid, bias, out, ws_src,
                                                    ws_nv, ctr);
    gemm_kernel<<<dim3(NWORK), dim3(256), 0, stream>>>(seq, W, bias, ws_src,
                                                       ws_nv, ctr, out);
}

// Round 10
// 34.279 us; speedup vs baseline: 1.5278x; 1.3876x over previous
//
#include <hip/hip_runtime.h>

#define B_ 128
#define S_ 512
#define H_ 1024
#define L_ 9
#define NB 512  // gemm blocks: exactly 2 per CU, equal static chunks

// ---- Kernel A: compaction map + pad-row outputs (wave-parallel) ----
__global__ __launch_bounds__(256) void prep_kernel(
    const int* __restrict__ valid, const float* __restrict__ bias,
    float* __restrict__ out, int* __restrict__ ws_src, int* __restrict__ ws_nv) {
    __shared__ int cnt[8];
    const int lane = threadIdx.x & 63;
    const int wv = threadIdx.x >> 6;
    const int b = blockIdx.x;
    const int* vrow = valid + (size_t)b * S_;

    int v0 = vrow[128 * wv + lane];
    int v1 = vrow[128 * wv + 64 + lane];
    unsigned long long m0 = __ballot(v0 != 0);
    unsigned long long m1 = __ballot(v1 != 0);
    if (lane == 0) { cnt[2 * wv] = __popcll(m0); cnt[2 * wv + 1] = __popcll(m1); }
    __syncthreads();

    int base0 = 0, total = 0;
#pragma unroll
    for (int k = 0; k < 8; ++k) {
        if (k < 2 * wv) base0 += cnt[k];
        total += cnt[k];
    }
    int base1 = base0 + cnt[2 * wv];
    if (v0) ws_src[b * S_ + base0 + __popcll(m0 & ((1ull << lane) - 1ull))] =
        128 * wv + lane;
    if (v1) ws_src[b * S_ + base1 + __popcll(m1 & ((1ull << lane) - 1ull))] =
        128 * wv + 64 + lane;
    if (threadIdx.x == 0) ws_nv[b] = total;

    // pad rows [total, 512): softmax(bias)
    float pv[L_];
    float mx = bias[0];
#pragma unroll
    for (int l = 1; l < L_; ++l) mx = fmaxf(mx, bias[l]);
    float s = 0.f;
#pragma unroll
    for (int l = 0; l < L_; ++l) { pv[l] = expf(bias[l] - mx); s += pv[l]; }
    float inv = 1.f / s;
#pragma unroll
    for (int l = 0; l < L_; ++l) pv[l] *= inv;
    for (int j = total + threadIdx.x; j < S_; j += 256) {
        float* op = out + ((size_t)b * S_ + j) * L_;
#pragma unroll
        for (int l = 0; l < L_; ++l) op[l] = pv[l];
    }
}

// ---- Kernel B: equal-chunk GEMM (R6 inner loop, balanced partitioning) ----
// 512 blocks, each owns chunk=ceil(total/512) contiguous dense rows, processed
// in 64-row tiles (4 waves x 16 rows; hl=lane&15 spans h, g=lane>>4 picks row,
// 4 row-slots/lane). W (36KB) in LDS once; 9x broadcast ds_read_b128/iter;
// 16-wide butterfly once per tile.
__global__ __launch_bounds__(256, 2) void gemm_kernel(
    const float* __restrict__ seq, const float* __restrict__ Wm,
    const float* __restrict__ bias, const int* __restrict__ ws_src,
    const int* __restrict__ ws_nv, float* __restrict__ out) {
    __shared__ __align__(16) float Wl[H_ * L_];  // 36,864 B
    __shared__ int offs[B_ + 1];
    __shared__ int srow[64], orow[64];

    const int tid = threadIdx.x;
    const int lane = tid & 63;
    const int wv = __builtin_amdgcn_readfirstlane(tid >> 6);
    const int hl = lane & 15;
    const int g = lane >> 4;

    if (tid < 64) {  // 128-wide exclusive prefix of ws_nv
        int s0 = ws_nv[lane], s1 = ws_nv[64 + lane];
#pragma unroll
        for (int d = 1; d < 64; d <<= 1) {
            int t0 = __shfl_up(s0, d, 64), t1 = __shfl_up(s1, d, 64);
            if (lane >= d) { s0 += t0; s1 += t1; }
        }
        int tot0 = __shfl(s0, 63, 64);
        offs[1 + lane] = s0;
        offs[65 + lane] = tot0 + s1;
        if (lane == 0) offs[0] = 0;
    }
    {  // cooperative W -> LDS
        const float4* Wg = (const float4*)Wm;
        float4* Wd = (float4*)Wl;
#pragma unroll
        for (int k = 0; k < 9; ++k) Wd[k * 256 + tid] = Wg[k * 256 + tid];
    }
    __syncthreads();

    const int total = offs[B_];
    const int chunk = (total + NB - 1) / NB;
    const int Gs = blockIdx.x * chunk;
    const int Ge = min(Gs + chunk, total);
    if (Gs >= Ge) return;  // block-uniform

    for (int t0 = Gs; t0 < Ge; t0 += 64) {
        // map this tile's rows (thread t -> tile row t)
        if (tid < 64) {
            int G = t0 + tid;
            int sa = -1, o = 0;
            if (G < Ge) {
                int lo = 0, hi = B_;
                while (hi - lo > 1) {
                    int mid = (lo + hi) >> 1;
                    if (offs[mid] <= G) lo = mid; else hi = mid;
                }
                int j = G - offs[lo];
                o = lo * S_ + j;
                sa = lo * S_ + ws_src[o];
            }
            srow[tid] = sa;  // -1 = outside this block's range
            orow[tid] = o;
        }
        __syncthreads();

        const float* rp[4];
#pragma unroll
        for (int s = 0; s < 4; ++s) {
            int sa = srow[16 * wv + 4 * s + g];
            rp[s] = seq + (size_t)(sa < 0 ? 0 : sa) * H_ + 4 * hl;
        }

        float acc[4][L_];
#pragma unroll
        for (int s = 0; s < 4; ++s)
#pragma unroll
            for (int l = 0; l < L_; ++l) acc[s][l] = 0.f;

#pragma unroll 2
        for (int it = 0; it < 16; ++it) {
            float4 xv0 = *(const float4*)(rp[0] + 64 * it);
            float4 xv1 = *(const float4*)(rp[1] + 64 * it);
            float4 xv2 = *(const float4*)(rp[2] + 64 * it);
            float4 xv3 = *(const float4*)(rp[3] + 64 * it);
            const float* wf = Wl + 36 * hl + 576 * it;
            float wr[36];
#pragma unroll
            for (int j = 0; j < 9; ++j)
                *(float4*)&wr[4 * j] = *(const float4*)(wf + 4 * j);
            float xk0[4] = {xv0.x, xv0.y, xv0.z, xv0.w};
            float xk1[4] = {xv1.x, xv1.y, xv1.z, xv1.w};
            float xk2[4] = {xv2.x, xv2.y, xv2.z, xv2.w};
            float xk3[4] = {xv3.x, xv3.y, xv3.z, xv3.w};
#pragma unroll
            for (int k = 0; k < 4; ++k)
#pragma unroll
                for (int l = 0; l < L_; ++l) {
                    float w = wr[9 * k + l];
                    acc[0][l] = fmaf(xk0[k], w, acc[0][l]);
                    acc[1][l] = fmaf(xk1[k], w, acc[1][l]);
                    acc[2][l] = fmaf(xk2[k], w, acc[2][l]);
                    acc[3][l] = fmaf(xk3[k], w, acc[3][l]);
                }
        }

        // 16-wide hl-butterfly (once per tile)
#pragma unroll
        for (int m = 1; m < 16; m <<= 1)
#pragma unroll
            for (int s = 0; s < 4; ++s)
#pragma unroll
                for (int l = 0; l < L_; ++l)
                    acc[s][l] += __shfl_xor(acc[s][l], m);

        // lanes hl<4 write row 16*wv + 4*hl + g
        if (hl < 4) {
            float v[L_];
#pragma unroll
            for (int s = 0; s < 4; ++s)
                if (hl == s) {
#pragma unroll
                    for (int l = 0; l < L_; ++l) v[l] = acc[s][l];
                }
            int rw = 16 * wv + 4 * hl + g;
            if (srow[rw] >= 0) {
#pragma unroll
                for (int l = 0; l < L_; ++l) v[l] += bias[l];
                float mx = v[0];
#pragma unroll
                for (int l = 1; l < L_; ++l) mx = fmaxf(mx, v[l]);
                float s = 0.f;
#pragma unroll
                for (int l = 0; l < L_; ++l) {
                    v[l] = expf(v[l] - mx);
                    s += v[l];
                }
                float inv = 1.f / s;
                float* op = out + (size_t)orow[rw] * L_;
#pragma unroll
                for (int l = 0; l < L_; ++l) op[l] = v[l] * inv;
            }
        }
        __syncthreads();  // protect srow/orow before next tile overwrites
    }
}

extern "C" void kernel_launch(void* const* d_in, const int* in_sizes, int n_in,
                              void* d_out, int out_size, void* d_ws, size_t ws_size,
                              hipStream_t stream) {
    const float* seq = (const float*)d_in[0];   // [B,S,H] f32
    const float* W = (const float*)d_in[1];     // [H,L] f32
    const float* bias = (const float*)d_in[2];  // [L] f32
    const int* valid = (const int*)d_in[3];     // [B,S] i32
    float* out = (float*)d_out;                 // [B,S,L] f32

    int* ws_src = (int*)d_ws;        // [128*512] within-batch source indices
    int* ws_nv = ws_src + B_ * S_;   // [128] valid counts

    prep_kernel<<<dim3(B_), dim3(256), 0, stream>>>(valid, bias, out, ws_src, ws_nv);
    gemm_kernel<<<dim3(NB), dim3(256), 0, stream>>>(seq, W, bias, ws_src, ws_nv,
                                                    out);
}